// Round 1
// baseline (282.831 us; speedup 1.0000x reference)
//
#include <hip/hip_runtime.h>
#include <hip/hip_bf16.h>
#include <stdint.h>

// Problem constants
#define N_NODES 8192
#define N_EDGES 16384
#define N_GRAPHS 512
#define IN_DIM 235
#define H_DIM 64
#define ED_DIM 52
#define HID1 128          // edge-MLP hidden width (W1 rows)
#define KP 256            // K padded 235 -> 256 for MFMA tiling
#define NB 3328           // ED_DIM * H_DIM = GEMM N dimension

typedef __bf16 bf16x8 __attribute__((ext_vector_type(8)));
typedef float f32x4 __attribute__((ext_vector_type(4)));

static __device__ inline unsigned short f2bf(float f) {
    union { float f; unsigned u; } v; v.f = f;
    unsigned r = v.u + 0x7FFFu + ((v.u >> 16) & 1u);   // RNE
    return (unsigned short)(r >> 16);
}
static __device__ inline float bf2f(unsigned short s) {
    union { unsigned u; float f; } v; v.u = ((unsigned)s) << 16;
    return v.f;
}

// ---------------------------------------------------------------------------
// K0a: compose edge-MLP weights (no nonlinearity between the two Linears):
// Bt[n=(d*64+h)][i] = sum_k W2[(i*64+h)*128+k] * W1[k*52+d], zero-padded i>=235
// Stored K-contiguous (bf16) so the GEMM B-fragment is a contiguous 16B read.
__global__ __launch_bounds__(256) void k_build_bt(const float* __restrict__ W1,
                                                  const float* __restrict__ W2,
                                                  unsigned short* __restrict__ Bt) {
    __shared__ float w1col[HID1];
    const int n = blockIdx.x;          // 0..3327
    const int d = n >> 6, h = n & 63;
    const int t = threadIdx.x;
    if (t < HID1) w1col[t] = W1[t * ED_DIM + d];
    __syncthreads();
    float acc = 0.f;
    if (t < IN_DIM) {
        const float4* w2r = (const float4*)(W2 + (size_t)(t * H_DIM + h) * HID1);
        #pragma unroll 8
        for (int k4 = 0; k4 < HID1 / 4; ++k4) {
            float4 w = w2r[k4];
            acc += w.x * w1col[k4 * 4 + 0] + w.y * w1col[k4 * 4 + 1]
                 + w.z * w1col[k4 * 4 + 2] + w.w * w1col[k4 * 4 + 3];
        }
    }
    Bt[(size_t)n * KP + t] = (t < IN_DIM) ? f2bf(acc) : (unsigned short)0;
}

// K0b: composed bias bc[j] = b2[j] + sum_k W2[j,k]*b1[k]   (j < 15040)
__global__ __launch_bounds__(256) void k_build_bc(const float* __restrict__ W2,
                                                  const float* __restrict__ b1,
                                                  const float* __restrict__ b2,
                                                  float* __restrict__ bc) {
    const int j = blockIdx.x * 256 + threadIdx.x;
    if (j >= IN_DIM * H_DIM) return;
    float acc = b2[j];
    const float* w = W2 + (size_t)j * HID1;
    #pragma unroll 8
    for (int k = 0; k < HID1; ++k) acc += w[k] * b1[k];
    bc[j] = acc;
}

// K1: x (fp32, [8192,235]) -> A (bf16, [8192,256] zero-padded)
__global__ __launch_bounds__(256) void k_build_a(const float* __restrict__ x,
                                                 unsigned short* __restrict__ A) {
    const int j = blockIdx.x * 256 + threadIdx.x;   // 0 .. 8192*256-1
    const int n = j >> 8, i = j & 255;
    A[j] = (i < IN_DIM) ? f2bf(x[n * IN_DIM + i]) : (unsigned short)0;
}

// ---------------------------------------------------------------------------
// K2: P = A @ Bt^T  : [8192,256] x [256,3328] -> bf16 [8192,3328]
// 128x128 block tile, BK=32, 4 waves (2x2), each wave 64x64 via 4x4 MFMA
// 16x16x32 bf16 tiles. m93-style simple LDS staging.
__global__ __launch_bounds__(256) void k_gemm(const unsigned short* __restrict__ A,
                                              const unsigned short* __restrict__ Bt,
                                              unsigned short* __restrict__ P) {
    __shared__ unsigned short As[128 * 32];
    __shared__ unsigned short Bs[128 * 32];
    const int t = threadIdx.x;
    const int m0 = blockIdx.y * 128, n0 = blockIdx.x * 128;
    const int wid = t >> 6, lane = t & 63;
    const int wm = wid >> 1, wn = wid & 1;
    const int q = lane >> 4, r16 = lane & 15;

    f32x4 acc[4][4] = {};

    for (int k0 = 0; k0 < KP; k0 += 32) {
        __syncthreads();
        #pragma unroll
        for (int r = 0; r < 2; ++r) {
            const int idx = r * 256 + t;          // 0..511, 8 shorts each
            const int row = idx >> 2, col = (idx & 3) * 8;
            *(uint4*)(&As[row * 32 + col]) =
                *(const uint4*)(&A[(size_t)(m0 + row) * KP + k0 + col]);
            *(uint4*)(&Bs[row * 32 + col]) =
                *(const uint4*)(&Bt[(size_t)(n0 + row) * KP + k0 + col]);
        }
        __syncthreads();
        bf16x8 af[4], bfr[4];
        #pragma unroll
        for (int mi = 0; mi < 4; ++mi)
            af[mi] = *(const bf16x8*)(&As[(wm * 64 + mi * 16 + r16) * 32 + q * 8]);
        #pragma unroll
        for (int ni = 0; ni < 4; ++ni)
            bfr[ni] = *(const bf16x8*)(&Bs[(wn * 64 + ni * 16 + r16) * 32 + q * 8]);
        #pragma unroll
        for (int mi = 0; mi < 4; ++mi)
            #pragma unroll
            for (int ni = 0; ni < 4; ++ni)
                acc[mi][ni] = __builtin_amdgcn_mfma_f32_16x16x32_bf16(
                    af[mi], bfr[ni], acc[mi][ni], 0, 0, 0);
    }

    // epilogue: C/D layout col=lane&15, row=quad*4+reg
    #pragma unroll
    for (int mi = 0; mi < 4; ++mi)
        #pragma unroll
        for (int ni = 0; ni < 4; ++ni) {
            const int col = n0 + wn * 64 + ni * 16 + r16;
            #pragma unroll
            for (int rr = 0; rr < 4; ++rr) {
                const int row = m0 + wm * 64 + mi * 16 + q * 4 + rr;
                P[(size_t)row * NB + col] = f2bf(acc[mi][ni][rr]);
            }
        }
}

// ---------------------------------------------------------------------------
// K3: per node (one wave, lane=h):
//   agg[n,h] = conv_b[h] + sum_i x[n,i]*root[i,h]   (NNConv root term)
//   xb2[n,h] = sum_i x[n,i]*bc[i*64+h]              (composed edge-MLP bias term)
__global__ __launch_bounds__(256) void k_node_lin(const float* __restrict__ x,
                                                  const float* __restrict__ root,
                                                  const float* __restrict__ conv_b,
                                                  const float* __restrict__ bc,
                                                  float* __restrict__ agg,
                                                  float* __restrict__ xb2) {
    const int n = (blockIdx.x * 256 + threadIdx.x) >> 6;
    const int h = threadIdx.x & 63;
    if (n >= N_NODES) return;
    const float* xr = x + (size_t)n * IN_DIM;
    float a = conv_b[h], b = 0.f;
    #pragma unroll 4
    for (int i = 0; i < IN_DIM; ++i) {
        const float xv = xr[i];
        a += xv * root[i * H_DIM + h];
        b += xv * bc[i * H_DIM + h];
    }
    agg[n * H_DIM + h] = a;
    xb2[n * H_DIM + h] = b;
}

// K4: per edge (one wave, lane=h):
//   msg[h] = xb2[src,h] + sum_d ea[e,d] * P[src, d*64+h];  atomicAdd into agg[dst]
__global__ __launch_bounds__(256) void k_edge(const int* __restrict__ ei,
                                              const float* __restrict__ ea,
                                              const unsigned short* __restrict__ P,
                                              const float* __restrict__ xb2,
                                              float* __restrict__ agg) {
    const int e = (blockIdx.x * 256 + threadIdx.x) >> 6;
    const int h = threadIdx.x & 63;
    if (e >= N_EDGES) return;
    const int s = ei[e], dst = ei[N_EDGES + e];
    const unsigned short* Pr = P + (size_t)s * NB;
    const float* ear = ea + (size_t)e * ED_DIM;
    float acc = xb2[s * H_DIM + h];
    #pragma unroll 4
    for (int d = 0; d < ED_DIM; ++d)
        acc += ear[d] * bf2f(Pr[d * H_DIM + h]);
    atomicAdd(&agg[dst * H_DIM + h], acc);
}

// K5: out = relu(agg); mean-pool accumulate per graph
__global__ __launch_bounds__(256) void k_pool(const float* __restrict__ agg,
                                              const int* __restrict__ batch,
                                              float* __restrict__ psum,
                                              float* __restrict__ pcnt) {
    const int n = (blockIdx.x * 256 + threadIdx.x) >> 6;
    const int h = threadIdx.x & 63;
    if (n >= N_NODES) return;
    const float v = fmaxf(agg[n * H_DIM + h], 0.f);
    const int g = batch[n];
    atomicAdd(&psum[g * H_DIM + h], v);
    if (h == 0) atomicAdd(&pcnt[g], 1.0f);
}

// K6: MLP head, one block per graph
__global__ __launch_bounds__(256) void k_head(const float* __restrict__ psum,
                                              const float* __restrict__ pcnt,
                                              const float* __restrict__ fw1, const float* __restrict__ fb1,
                                              const float* __restrict__ fw2, const float* __restrict__ fb2,
                                              const float* __restrict__ fw3, const float* __restrict__ fb3,
                                              const float* __restrict__ fw4, const float* __restrict__ fb4,
                                              float* __restrict__ out) {
    __shared__ float sp[64], s1[128], s2[256], s3[128];
    const int g = blockIdx.x, t = threadIdx.x;
    if (t < 64) sp[t] = psum[g * 64 + t] / fmaxf(pcnt[g], 1.0f);
    __syncthreads();
    if (t < 128) {
        float a = fb1[t];
        const float* w = fw1 + t * 64;
        #pragma unroll 8
        for (int k = 0; k < 64; ++k) a += sp[k] * w[k];
        s1[t] = fmaxf(a, 0.f);
    }
    __syncthreads();
    {
        float a = fb2[t];
        const float* w = fw2 + t * 128;
        #pragma unroll 8
        for (int k = 0; k < 128; ++k) a += s1[k] * w[k];
        s2[t] = fmaxf(a, 0.f);
    }
    __syncthreads();
    if (t < 128) {
        float a = fb3[t];
        const float* w = fw3 + t * 256;
        #pragma unroll 8
        for (int k = 0; k < 256; ++k) a += s2[k] * w[k];
        s3[t] = fmaxf(a, 0.f);
    }
    __syncthreads();
    if (t < 64) {
        float p = s3[t] * fw4[t] + s3[t + 64] * fw4[t + 64];
        #pragma unroll
        for (int off = 32; off > 0; off >>= 1) p += __shfl_down(p, off);
        if (t == 0) out[g] = p + fb4[0];
    }
}

// ---------------------------------------------------------------------------
extern "C" void kernel_launch(void* const* d_in, const int* in_sizes, int n_in,
                              void* d_out, int out_size, void* d_ws, size_t ws_size,
                              hipStream_t stream) {
    const float* x      = (const float*)d_in[0];
    const int*   ei     = (const int*)d_in[1];
    const float* ea     = (const float*)d_in[2];
    const int*   batch  = (const int*)d_in[3];
    const float* W1     = (const float*)d_in[4];
    const float* b1     = (const float*)d_in[5];
    const float* W2     = (const float*)d_in[6];
    const float* b2     = (const float*)d_in[7];
    const float* root   = (const float*)d_in[8];
    const float* conv_b = (const float*)d_in[9];
    const float* fw1 = (const float*)d_in[10]; const float* fb1 = (const float*)d_in[11];
    const float* fw2 = (const float*)d_in[12]; const float* fb2 = (const float*)d_in[13];
    const float* fw3 = (const float*)d_in[14]; const float* fb3 = (const float*)d_in[15];
    const float* fw4 = (const float*)d_in[16]; const float* fb4 = (const float*)d_in[17];
    float* out = (float*)d_out;

    char* ws = (char*)d_ws;
    // workspace layout (16B-aligned offsets), total ~64.8 MB
    unsigned short* A   = (unsigned short*)(ws);             // 8192*256*2   = 4,194,304
    unsigned short* Bt  = (unsigned short*)(ws + 4194304);   // 3328*256*2   = 1,703,936
    unsigned short* P   = (unsigned short*)(ws + 5898240);   // 8192*3328*2  = 54,525,952
    float* agg  = (float*)(ws + 60424192);                   // 8192*64*4    = 2,097,152
    float* xb2  = (float*)(ws + 62521344);                   // 8192*64*4    = 2,097,152
    float* bc   = (float*)(ws + 64618496);                   // 15040*4      = 60,160
    float* psum = (float*)(ws + 64678656);                   // 512*64*4     = 131,072
    float* pcnt = (float*)(ws + 64809728);                   // 512*4        = 2,048

    // psum + pcnt are contiguous: zero both in one memset (ws is poisoned 0xAA)
    hipMemsetAsync(psum, 0, (size_t)(N_GRAPHS * H_DIM + N_GRAPHS) * sizeof(float), stream);

    k_build_bc<<<dim3((IN_DIM * H_DIM + 255) / 256), dim3(256), 0, stream>>>(W2, b1, b2, bc);
    k_build_bt<<<dim3(NB), dim3(256), 0, stream>>>(W1, W2, Bt);
    k_build_a<<<dim3(N_NODES), dim3(256), 0, stream>>>(x, A);
    k_gemm<<<dim3(NB / 128, N_NODES / 128), dim3(256), 0, stream>>>(A, Bt, P);
    k_node_lin<<<dim3(N_NODES / 4), dim3(256), 0, stream>>>(x, root, conv_b, bc, agg, xb2);
    k_edge<<<dim3(N_EDGES / 4), dim3(256), 0, stream>>>(ei, ea, P, xb2, agg);
    k_pool<<<dim3(N_NODES / 4), dim3(256), 0, stream>>>(agg, batch, psum, pcnt);
    k_head<<<dim3(N_GRAPHS), dim3(256), 0, stream>>>(psum, pcnt, fw1, fb1, fw2, fb2, fw3, fb3, fw4, fb4, out);
}

// Round 2
// 219.754 us; speedup vs baseline: 1.2870x; 1.2870x over previous
//
#include <hip/hip_runtime.h>
#include <hip/hip_bf16.h>
#include <stdint.h>

// Problem constants
#define N_NODES 8192
#define N_EDGES 16384
#define N_GRAPHS 512
#define IN_DIM 235
#define H_DIM 64
#define ED_DIM 52
#define HID1 128          // edge-MLP hidden width (W1 rows)
#define KP 256            // K padded 235 -> 256 for MFMA tiling
#define NB 3328           // ED_DIM * H_DIM = P column count
#define NBE 3456          // NB + 64 (root) + 64 (bc) extra GEMM columns

typedef __bf16 bf16x8 __attribute__((ext_vector_type(8)));
typedef float f32x4 __attribute__((ext_vector_type(4)));

static __device__ inline unsigned short f2bf(float f) {
    union { float f; unsigned u; } v; v.f = f;
    unsigned r = v.u + 0x7FFFu + ((v.u >> 16) & 1u);   // RNE
    return (unsigned short)(r >> 16);
}
static __device__ inline float bf2f(unsigned short s) {
    union { unsigned u; float f; } v; v.u = ((unsigned)s) << 16;
    return v.f;
}

// ---------------------------------------------------------------------------
// K0a: compose edge-MLP weights (no nonlinearity between the two Linears):
// Bt[n=(d*64+h)][i] = sum_k W2[(i*64+h)*128+k] * W1[k*52+d]
// One block per i; W1 fully staged in LDS (26.6 KB), the block's 64 W2 rows
// staged in LDS (row-padded to 129 floats to break the 64-way bank conflict).
// W2 is read from global exactly once across the whole grid.
__global__ __launch_bounds__(256) void k_build_bt(const float* __restrict__ W1,
                                                  const float* __restrict__ W2,
                                                  unsigned short* __restrict__ Bt) {
    __shared__ float w1s[HID1 * ED_DIM];      // [k][d]
    __shared__ float w2s[64 * 129];           // [h][k] padded
    const int i = blockIdx.x;                 // 0..234
    const int t = threadIdx.x;
    for (int j = t; j < HID1 * ED_DIM; j += 256) w1s[j] = W1[j];
    const float* w2src = W2 + (size_t)i * 64 * HID1;   // rows i*64 .. i*64+63, contiguous
    for (int j = t; j < 64 * HID1; j += 256) w2s[(j >> 7) * 129 + (j & 127)] = w2src[j];
    __syncthreads();
    for (int p = t; p < NB; p += 256) {       // p = d*64 + h
        const int d = p >> 6, h = p & 63;
        float acc = 0.f;
        #pragma unroll 8
        for (int k = 0; k < HID1; ++k)
            acc += w1s[k * ED_DIM + d] * w2s[h * 129 + k];
        Bt[(size_t)p * KP + i] = f2bf(acc);
    }
}

// K0b: composed bias bc[j] = b2[j] + sum_k W2[j,k]*b1[k]   (j < 15040)
__global__ __launch_bounds__(256) void k_build_bc(const float* __restrict__ W2,
                                                  const float* __restrict__ b1,
                                                  const float* __restrict__ b2,
                                                  float* __restrict__ bc) {
    const int j = blockIdx.x * 256 + threadIdx.x;
    if (j >= IN_DIM * H_DIM) return;
    float acc = b2[j];
    const float* w = W2 + (size_t)j * HID1;
    #pragma unroll 8
    for (int k = 0; k < HID1; ++k) acc += w[k] * b1[k];
    bc[j] = acc;
}

// K0c: extra GEMM columns: 3328+j (j<64) = root col j; 3392+j = bc col j.
// Pad rows i>=235 are already zero from the Bt memset.
__global__ __launch_bounds__(256) void k_build_ext(const float* __restrict__ root,
                                                   const float* __restrict__ bc,
                                                   unsigned short* __restrict__ Bt) {
    const int j = blockIdx.x;        // 0..127
    const int i = threadIdx.x;       // 0..255
    if (i >= IN_DIM) return;
    const float v = (j < 64) ? root[i * H_DIM + j] : bc[i * H_DIM + (j - 64)];
    Bt[(size_t)(NB + j) * KP + i] = f2bf(v);
}

// K1: x (fp32, [8192,235]) -> A (bf16, [8192,256] zero-padded)
__global__ __launch_bounds__(256) void k_build_a(const float* __restrict__ x,
                                                 unsigned short* __restrict__ A) {
    const int j = blockIdx.x * 256 + threadIdx.x;
    const int n = j >> 8, i = j & 255;
    A[j] = (i < IN_DIM) ? f2bf(x[n * IN_DIM + i]) : (unsigned short)0;
}

// ---------------------------------------------------------------------------
// K2: [8192,256] x [256,3456] GEMM. Cols <3328 -> P (bf16). Cols 3328..3391 ->
// agg (fp32, +conv_b). Cols 3392..3455 -> xb2 (fp32).
// 128x128 tile, BK=32, 4 waves, 4x4 16x16x32 MFMA per wave, async
// global_load_lds width-16 staging (LDS layout is idx*16 contiguous per wave).
__global__ __launch_bounds__(256) void k_gemm(const unsigned short* __restrict__ A,
                                              const unsigned short* __restrict__ Bt,
                                              unsigned short* __restrict__ P,
                                              float* __restrict__ agg,
                                              float* __restrict__ xb2,
                                              const float* __restrict__ conv_b) {
    __shared__ unsigned short As[128 * 32];
    __shared__ unsigned short Bs[128 * 32];
    const int t = threadIdx.x;
    const int m0 = blockIdx.y * 128, n0 = blockIdx.x * 128;
    const int wid = t >> 6, lane = t & 63;
    const int wm = wid >> 1, wn = wid & 1;
    const int q = lane >> 4, r16 = lane & 15;

    f32x4 acc[4][4] = {};

    for (int k0 = 0; k0 < KP; k0 += 32) {
        __syncthreads();
        #pragma unroll
        for (int r = 0; r < 2; ++r) {
            const int idx = r * 256 + t;              // 0..511
            const int row = idx >> 2, col = (idx & 3) * 8;
            const unsigned short* ga = &A[(size_t)(m0 + row) * KP + k0 + col];
            const unsigned short* gb = &Bt[(size_t)(n0 + row) * KP + k0 + col];
            // wave-uniform LDS base; HW scatters lane L at base + L*16
            char* la = (char*)As + r * 4096 + wid * 1024;
            char* lb = (char*)Bs + r * 4096 + wid * 1024;
            __builtin_amdgcn_global_load_lds(
                (const __attribute__((address_space(1))) unsigned int*)ga,
                (__attribute__((address_space(3))) unsigned int*)la, 16, 0, 0);
            __builtin_amdgcn_global_load_lds(
                (const __attribute__((address_space(1))) unsigned int*)gb,
                (__attribute__((address_space(3))) unsigned int*)lb, 16, 0, 0);
        }
        __syncthreads();
        bf16x8 af[4], bfr[4];
        #pragma unroll
        for (int mi = 0; mi < 4; ++mi)
            af[mi] = *(const bf16x8*)(&As[(wm * 64 + mi * 16 + r16) * 32 + q * 8]);
        #pragma unroll
        for (int ni = 0; ni < 4; ++ni)
            bfr[ni] = *(const bf16x8*)(&Bs[(wn * 64 + ni * 16 + r16) * 32 + q * 8]);
        #pragma unroll
        for (int mi = 0; mi < 4; ++mi)
            #pragma unroll
            for (int ni = 0; ni < 4; ++ni)
                acc[mi][ni] = __builtin_amdgcn_mfma_f32_16x16x32_bf16(
                    af[mi], bfr[ni], acc[mi][ni], 0, 0, 0);
    }

    // epilogue: C/D layout col=lane&15, row=quad*4+reg
    #pragma unroll
    for (int mi = 0; mi < 4; ++mi)
        #pragma unroll
        for (int ni = 0; ni < 4; ++ni) {
            const int c = n0 + wn * 64 + ni * 16 + r16;
            #pragma unroll
            for (int rr = 0; rr < 4; ++rr) {
                const int row = m0 + wm * 64 + mi * 16 + q * 4 + rr;
                const float v = acc[mi][ni][rr];
                if (c < NB) {
                    P[(size_t)row * NB + c] = f2bf(v);
                } else if (c < NB + 64) {
                    agg[row * H_DIM + (c - NB)] = v + conv_b[c - NB];
                } else {
                    xb2[row * H_DIM + (c - NB - 64)] = v;
                }
            }
        }
}

// ---------------------------------------------------------------------------
// K4: per edge (one wave, lane=h):
//   msg[h] = xb2[src,h] + sum_d ea[e,d] * P[src, d*64+h];  atomicAdd into agg[dst]
__global__ __launch_bounds__(256) void k_edge(const int* __restrict__ ei,
                                              const float* __restrict__ ea,
                                              const unsigned short* __restrict__ P,
                                              const float* __restrict__ xb2,
                                              float* __restrict__ agg) {
    const int e = (blockIdx.x * 256 + threadIdx.x) >> 6;
    const int h = threadIdx.x & 63;
    if (e >= N_EDGES) return;
    const int s = ei[e], dst = ei[N_EDGES + e];
    const unsigned short* Pr = P + (size_t)s * NB;
    const float* ear = ea + (size_t)e * ED_DIM;
    float acc = xb2[s * H_DIM + h];
    #pragma unroll 4
    for (int d = 0; d < ED_DIM; ++d)
        acc += ear[d] * bf2f(Pr[d * H_DIM + h]);
    atomicAdd(&agg[dst * H_DIM + h], acc);
}

// K5: out = relu(agg); mean-pool accumulate per graph
__global__ __launch_bounds__(256) void k_pool(const float* __restrict__ agg,
                                              const int* __restrict__ batch,
                                              float* __restrict__ psum,
                                              float* __restrict__ pcnt) {
    const int n = (blockIdx.x * 256 + threadIdx.x) >> 6;
    const int h = threadIdx.x & 63;
    if (n >= N_NODES) return;
    const float v = fmaxf(agg[n * H_DIM + h], 0.f);
    const int g = batch[n];
    atomicAdd(&psum[g * H_DIM + h], v);
    if (h == 0) atomicAdd(&pcnt[g], 1.0f);
}

// K6: MLP head, one block per graph
__global__ __launch_bounds__(256) void k_head(const float* __restrict__ psum,
                                              const float* __restrict__ pcnt,
                                              const float* __restrict__ fw1, const float* __restrict__ fb1,
                                              const float* __restrict__ fw2, const float* __restrict__ fb2,
                                              const float* __restrict__ fw3, const float* __restrict__ fb3,
                                              const float* __restrict__ fw4, const float* __restrict__ fb4,
                                              float* __restrict__ out) {
    __shared__ float sp[64], s1[128], s2[256], s3[128];
    const int g = blockIdx.x, t = threadIdx.x;
    if (t < 64) sp[t] = psum[g * 64 + t] / fmaxf(pcnt[g], 1.0f);
    __syncthreads();
    if (t < 128) {
        float a = fb1[t];
        const float* w = fw1 + t * 64;
        #pragma unroll 8
        for (int k = 0; k < 64; ++k) a += sp[k] * w[k];
        s1[t] = fmaxf(a, 0.f);
    }
    __syncthreads();
    {
        float a = fb2[t];
        const float* w = fw2 + t * 128;
        #pragma unroll 8
        for (int k = 0; k < 128; ++k) a += s1[k] * w[k];
        s2[t] = fmaxf(a, 0.f);
    }
    __syncthreads();
    if (t < 128) {
        float a = fb3[t];
        const float* w = fw3 + t * 256;
        #pragma unroll 8
        for (int k = 0; k < 256; ++k) a += s2[k] * w[k];
        s3[t] = fmaxf(a, 0.f);
    }
    __syncthreads();
    if (t < 64) {
        float p = s3[t] * fw4[t] + s3[t + 64] * fw4[t + 64];
        #pragma unroll
        for (int off = 32; off > 0; off >>= 1) p += __shfl_down(p, off);
        if (t == 0) out[g] = p + fb4[0];
    }
}

// ---------------------------------------------------------------------------
extern "C" void kernel_launch(void* const* d_in, const int* in_sizes, int n_in,
                              void* d_out, int out_size, void* d_ws, size_t ws_size,
                              hipStream_t stream) {
    const float* x      = (const float*)d_in[0];
    const int*   ei     = (const int*)d_in[1];
    const float* ea     = (const float*)d_in[2];
    const int*   batch  = (const int*)d_in[3];
    const float* W1     = (const float*)d_in[4];
    const float* b1     = (const float*)d_in[5];
    const float* W2     = (const float*)d_in[6];
    const float* b2     = (const float*)d_in[7];
    const float* root   = (const float*)d_in[8];
    const float* conv_b = (const float*)d_in[9];
    const float* fw1 = (const float*)d_in[10]; const float* fb1 = (const float*)d_in[11];
    const float* fw2 = (const float*)d_in[12]; const float* fb2 = (const float*)d_in[13];
    const float* fw3 = (const float*)d_in[14]; const float* fb3 = (const float*)d_in[15];
    const float* fw4 = (const float*)d_in[16]; const float* fb4 = (const float*)d_in[17];
    float* out = (float*)d_out;

    char* ws = (char*)d_ws;
    // workspace layout (16B-aligned), total ~64.9 MB
    unsigned short* A   = (unsigned short*)(ws);             // 8192*256*2   = 4,194,304
    unsigned short* Bt  = (unsigned short*)(ws + 4194304);   // 3456*256*2   = 1,769,472
    unsigned short* P   = (unsigned short*)(ws + 5963776);   // 8192*3328*2  = 54,525,952
    float* agg  = (float*)(ws + 60489728);                   // 8192*64*4    = 2,097,152
    float* xb2  = (float*)(ws + 62586880);                   // 8192*64*4    = 2,097,152
    float* bc   = (float*)(ws + 64684032);                   // 15040*4      = 60,160
    float* psum = (float*)(ws + 64744192);                   // 512*64*4     = 131,072
    float* pcnt = (float*)(ws + 64875264);                   // 512*4       = 2,048

    // Bt must start zeroed (pad cols i>=235); psum/pcnt contiguous -> one memset
    hipMemsetAsync(Bt, 0, (size_t)NBE * KP * sizeof(unsigned short), stream);
    hipMemsetAsync(psum, 0, (size_t)(N_GRAPHS * H_DIM + N_GRAPHS) * sizeof(float), stream);

    k_build_bc<<<dim3((IN_DIM * H_DIM + 255) / 256), dim3(256), 0, stream>>>(W2, b1, b2, bc);
    k_build_bt<<<dim3(IN_DIM), dim3(256), 0, stream>>>(W1, W2, Bt);
    k_build_ext<<<dim3(128), dim3(256), 0, stream>>>(root, bc, Bt);
    k_build_a<<<dim3(N_NODES), dim3(256), 0, stream>>>(x, A);
    k_gemm<<<dim3(NBE / 128, N_NODES / 128), dim3(256), 0, stream>>>(A, Bt, P, agg, xb2, conv_b);
    k_edge<<<dim3(N_EDGES / 4), dim3(256), 0, stream>>>(ei, ea, P, xb2, agg);
    k_pool<<<dim3(N_NODES / 4), dim3(256), 0, stream>>>(agg, batch, psum, pcnt);
    k_head<<<dim3(N_GRAPHS), dim3(256), 0, stream>>>(psum, pcnt, fw1, fb1, fw2, fb2, fw3, fb3, fw4, fb4, out);
}